// Round 6
// baseline (36.107 us; speedup 1.0000x reference)
//
#include <hip/hip_runtime.h>

// AdLIF neuron scan, two-kernel split.
//   Kernel A (scan): 1 thread/channel, 512 waves. Loads-only vmcnt FIFO:
//     U=64 ping-pong register batches (compute/group ~1024cy > HBM latency
//     ~900cy -> latency hidden). Spikes bitpacked, 16 u32/thread, written
//     coalesced to ws in [word][channel] layout (2 MB).
//   Kernel B (expand): 2048 waves, reads ws as uint4 (L2-resident), writes
//     output as float4 NT stores (1KB/wave-inst) -> pure write-BW regime.
//
// FP order matches the JAX reference exactly (mul then add, round-to-nearest,
// NO fma contraction) so spike decisions are bit-stable vs the reference.

#define T_STEPS 512
#define D_DIM   1024
#define N_CHAN  32768               // B * D

// f32(np.exp(-1/20)), f32(np.exp(-1/200))
#define ALPHA_MEM 0.9512294245007141f
#define ALPHA_ADP 0.9950124791926823f

typedef float f32x4 __attribute__((ext_vector_type(4)));

__device__ __forceinline__ bool adlif_step(float xv, float& v, float& a) {
    // v = alpha_mem * v + x_t
    v = __fadd_rn(__fmul_rn(ALPHA_MEM, v), xv);
    // cur_thr = THRESHOLD + BETA * a  (1.0 + 0.1*a)
    float cur = __fadd_rn(1.0f, __fmul_rn(0.1f, a));
    // s = (v - cur_thr >= THRESHOLD)   -- threshold counts twice, per ref
    float u = __fsub_rn(v, cur);
    bool fired = (u >= 1.0f);
    float s = fired ? 1.0f : 0.0f;
    // a = alpha_adp * a + s
    a = __fadd_rn(__fmul_rn(ALPHA_ADP, a), s);
    // v = v - s * THRESHOLD  (THRESHOLD = 1, exact)
    v = __fsub_rn(v, s);
    return fired;
}

// ---------------- Kernel A: scan + bitpack ----------------
__global__ __launch_bounds__(64) void adlif_scan(const float* __restrict__ x,
                                                 unsigned* __restrict__ wsbits) {
    const int idx = blockIdx.x * 64 + threadIdx.x;    // channel 0..32767
    const int b = idx >> 10;
    const int d = idx & (D_DIM - 1);
    const size_t base = (size_t)b * (T_STEPS * D_DIM) + d;
    const float* xp = x + base;

    float v = 0.0f, a = 0.0f;

    constexpr int U = 64;
    float buf0[U], buf1[U];

#pragma unroll
    for (int i = 0; i < U; ++i) buf0[i] = xp[i * D_DIM];

    for (int it = 0; it < T_STEPS / (2 * U); ++it) {  // 4 rolled iterations
        const int t0 = it * 2 * U;

        // prefetch group B (t0+64 .. t0+127)
#pragma unroll
        for (int i = 0; i < U; ++i) buf1[i] = xp[(t0 + U + i) * D_DIM];

        // compute group A -> 2 packed words, stored straight to ws
        unsigned wA0 = 0u, wA1 = 0u;
#pragma unroll
        for (int i = 0; i < U; ++i) {
            bool f = adlif_step(buf0[i], v, a);
            if (i < 32) wA0 |= ((unsigned)f) << i;
            else        wA1 |= ((unsigned)f) << (i - 32);
        }
        wsbits[(it * 4 + 0) * N_CHAN + idx] = wA0;
        wsbits[(it * 4 + 1) * N_CHAN + idx] = wA1;

        // prefetch group A for next iteration
        if (it + 1 < T_STEPS / (2 * U)) {
#pragma unroll
            for (int i = 0; i < U; ++i) buf0[i] = xp[(t0 + 2 * U + i) * D_DIM];
        }

        // compute group B -> 2 packed words
        unsigned wB0 = 0u, wB1 = 0u;
#pragma unroll
        for (int i = 0; i < U; ++i) {
            bool f = adlif_step(buf1[i], v, a);
            if (i < 32) wB0 |= ((unsigned)f) << i;
            else        wB1 |= ((unsigned)f) << (i - 32);
        }
        wsbits[(it * 4 + 2) * N_CHAN + idx] = wB0;
        wsbits[(it * 4 + 3) * N_CHAN + idx] = wB1;
    }
}

// ---------------- Kernel B: bit expand + f32 store ----------------
// grid: 32 (b) x 16 (word) = 512 blocks, 256 threads.
__global__ __launch_bounds__(256) void adlif_expand(const unsigned* __restrict__ wsbits,
                                                    float* __restrict__ out) {
    const int b = blockIdx.x >> 4;
    const int w = blockIdx.x & 15;
    const int d0 = threadIdx.x * 4;                   // 4 channels per thread
    const int c0 = (b << 10) + d0;

    const uint4 wd = *reinterpret_cast<const uint4*>(&wsbits[(size_t)w * N_CHAN + c0]);

    float* op = out + ((size_t)b * T_STEPS + w * 32) * D_DIM + d0;

#pragma unroll
    for (int k = 0; k < 32; ++k) {
        f32x4 val;
        val.x = (float)((wd.x >> k) & 1u);
        val.y = (float)((wd.y >> k) & 1u);
        val.z = (float)((wd.z >> k) & 1u);
        val.w = (float)((wd.w >> k) & 1u);
        __builtin_nontemporal_store(val, (f32x4*)(op + (size_t)k * D_DIM));
    }
}

// ---------------- Fallback (ws too small): round-5 single kernel ----------------
__global__ __launch_bounds__(64) void adlif_single(const float* __restrict__ x,
                                                   float* __restrict__ out) {
    __shared__ unsigned sbits[64 * 17];
    const int tid = threadIdx.x;
    const int idx = blockIdx.x * 64 + tid;
    const int b = idx >> 10;
    const int d = idx & (D_DIM - 1);
    const size_t base = (size_t)b * (T_STEPS * D_DIM) + d;
    const float* xp = x + base;
    float* op = out + base;

    float v = 0.0f, a = 0.0f;
    constexpr int U = 32;
    float buf0[U], buf1[U];
#pragma unroll
    for (int i = 0; i < U; ++i) buf0[i] = xp[i * D_DIM];
    for (int it = 0; it < T_STEPS / (2 * U); ++it) {
        const int t0 = it * 2 * U;
#pragma unroll
        for (int i = 0; i < U; ++i) buf1[i] = xp[(t0 + U + i) * D_DIM];
        unsigned wA = 0u;
#pragma unroll
        for (int i = 0; i < U; ++i) { bool f = adlif_step(buf0[i], v, a); wA |= ((unsigned)f) << i; }
        sbits[tid * 17 + it * 2] = wA;
        if (it + 1 < T_STEPS / (2 * U)) {
#pragma unroll
            for (int i = 0; i < U; ++i) buf0[i] = xp[(t0 + 2 * U + i) * D_DIM];
        }
        unsigned wB = 0u;
#pragma unroll
        for (int i = 0; i < U; ++i) { bool f = adlif_step(buf1[i], v, a); wB |= ((unsigned)f) << i; }
        sbits[tid * 17 + it * 2 + 1] = wB;
    }
    for (int w = 0; w < T_STEPS / 32; ++w) {
        const unsigned wb = sbits[tid * 17 + w];
#pragma unroll
        for (int k = 0; k < 32; ++k) {
            float s = (float)((wb >> k) & 1u);
            __builtin_nontemporal_store(s, &op[(size_t)(w * 32 + k) * D_DIM]);
        }
    }
}

extern "C" void kernel_launch(void* const* d_in, const int* in_sizes, int n_in,
                              void* d_out, int out_size, void* d_ws, size_t ws_size,
                              hipStream_t stream) {
    const float* x = (const float*)d_in[0];
    float* out = (float*)d_out;

    const size_t need = (size_t)N_CHAN * (T_STEPS / 32) * sizeof(unsigned);  // 2 MB

    if (ws_size >= need) {
        unsigned* wsbits = (unsigned*)d_ws;
        adlif_scan<<<N_CHAN / 64, 64, 0, stream>>>(x, wsbits);
        adlif_expand<<<32 * 16, 256, 0, stream>>>(wsbits, out);
    } else {
        adlif_single<<<N_CHAN / 64, 64, 0, stream>>>(x, out);
    }
}

// Round 7
// 34.336 us; speedup vs baseline: 1.0516x; 1.0516x over previous
//
#include <hip/hip_runtime.h>

// AdLIF neuron scan, two-kernel split, manual counted-vmcnt load window.
//
//  Kernel A (scan): 1 thread/channel, 512 waves. 64-deep rotating load
//    window in inline asm: per step {s_waitcnt vmcnt(63); sched_barrier(0);
//    consume buf[j]; global_load_dword buf[j] <- x[t+64]}. The asm loads are
//    invisible to the compiler's waitcnt logic -> no drain-all waits; each
//    wave keeps ~64 loads permanently in flight (8.4 MB machine-wide).
//    Spikes bitpacked, 2 u32 stores per 64 steps to ws [word][chan].
//  Kernel B (expand): reads ws as uint4, writes f32 output as float4 NT
//    stores (proven fast in round 6).
//
// FP order matches the JAX reference exactly (mul then add, round-to-nearest,
// NO fma contraction) so spike decisions are bit-stable vs the reference.

#define T_STEPS 512
#define D_DIM   1024
#define N_CHAN  32768               // B * D

// f32(np.exp(-1/20)), f32(np.exp(-1/200))
#define ALPHA_MEM 0.9512294245007141f
#define ALPHA_ADP 0.9950124791926823f

typedef float f32x4 __attribute__((ext_vector_type(4)));

__device__ __forceinline__ bool adlif_step(float xv, float& v, float& a) {
    // v = alpha_mem * v + x_t
    v = __fadd_rn(__fmul_rn(ALPHA_MEM, v), xv);
    // cur_thr = THRESHOLD + BETA * a  (1.0 + 0.1*a)
    float cur = __fadd_rn(1.0f, __fmul_rn(0.1f, a));
    // s = (v - cur_thr >= THRESHOLD)   -- threshold counts twice, per ref
    float u = __fsub_rn(v, cur);
    bool fired = (u >= 1.0f);
    float s = fired ? 1.0f : 0.0f;
    // a = alpha_adp * a + s
    a = __fadd_rn(__fmul_rn(ALPHA_ADP, a), s);
    // v = v - s * THRESHOLD  (THRESHOLD = 1, exact)
    v = __fsub_rn(v, s);
    return fired;
}

// Inline-asm load: compiler does not track it -> cannot insert drain waits.
#define ASM_LOAD(dst, ptr) \
    asm volatile("global_load_dword %0, %1, off" : "=v"(dst) : "v"(ptr) : "memory")
// Counted wait: oldest window slot has landed. sched_barrier(0) fences the
// consumer FP ops from hoisting above the waitcnt (guide rule #18).
#define ASM_VMCNT_63() \
    do { asm volatile("s_waitcnt vmcnt(63)" ::: "memory"); \
         __builtin_amdgcn_sched_barrier(0); } while (0)
#define ASM_VMCNT_0() \
    do { asm volatile("s_waitcnt vmcnt(0)" ::: "memory"); \
         __builtin_amdgcn_sched_barrier(0); } while (0)

// ---------------- Kernel A: scan + bitpack ----------------
__global__ __launch_bounds__(64) void adlif_scan(const float* __restrict__ x,
                                                 unsigned* __restrict__ wsbits) {
    const int idx = blockIdx.x * 64 + threadIdx.x;    // channel 0..32767
    const int b = idx >> 10;
    const int d = idx & (D_DIM - 1);
    const float* xp = x + (size_t)b * (T_STEPS * D_DIM) + d;

    float v = 0.0f, a = 0.0f;
    float buf[64];

    // prologue: fill the 64-deep window (64 loads outstanding)
#pragma unroll
    for (int j = 0; j < 64; ++j) ASM_LOAD(buf[j], xp + j * D_DIM);

#pragma unroll 1
    for (int it = 0; it < 7; ++it) {                  // steps 0 .. 447
        const int t0 = it * 64;
        unsigned wlo = 0u, whi = 0u;
#pragma unroll
        for (int j = 0; j < 64; ++j) {
            ASM_VMCNT_63();                            // slot j has landed
            bool f = adlif_step(buf[j], v, a);
            if (j < 32) wlo |= ((unsigned)f) << j;
            else        whi |= ((unsigned)f) << (j - 32);
            ASM_LOAD(buf[j], xp + (t0 + 64 + j) * D_DIM);  // refill for t+64
        }
        wsbits[(size_t)(it * 2 + 0) * N_CHAN + idx] = wlo;
        wsbits[(size_t)(it * 2 + 1) * N_CHAN + idx] = whi;
    }

    // tail: consume the final window (steps 448 .. 511), no refills
    {
        unsigned wlo = 0u, whi = 0u;
        ASM_VMCNT_0();
#pragma unroll
        for (int j = 0; j < 64; ++j) {
            bool f = adlif_step(buf[j], v, a);
            if (j < 32) wlo |= ((unsigned)f) << j;
            else        whi |= ((unsigned)f) << (j - 32);
        }
        wsbits[(size_t)14 * N_CHAN + idx] = wlo;
        wsbits[(size_t)15 * N_CHAN + idx] = whi;
    }
}

// ---------------- Kernel B: bit expand + f32 store ----------------
// grid: 32 (b) x 16 (word) = 512 blocks, 256 threads.
__global__ __launch_bounds__(256) void adlif_expand(const unsigned* __restrict__ wsbits,
                                                    float* __restrict__ out) {
    const int b = blockIdx.x >> 4;
    const int w = blockIdx.x & 15;
    const int d0 = threadIdx.x * 4;                   // 4 channels per thread
    const int c0 = (b << 10) + d0;

    const uint4 wd = *reinterpret_cast<const uint4*>(&wsbits[(size_t)w * N_CHAN + c0]);

    float* op = out + ((size_t)b * T_STEPS + w * 32) * D_DIM + d0;

#pragma unroll
    for (int k = 0; k < 32; ++k) {
        f32x4 val;
        val.x = (float)((wd.x >> k) & 1u);
        val.y = (float)((wd.y >> k) & 1u);
        val.z = (float)((wd.z >> k) & 1u);
        val.w = (float)((wd.w >> k) & 1u);
        __builtin_nontemporal_store(val, (f32x4*)(op + (size_t)k * D_DIM));
    }
}

// ---------------- Fallback (ws too small): round-5 single kernel ----------------
__global__ __launch_bounds__(64) void adlif_single(const float* __restrict__ x,
                                                   float* __restrict__ out) {
    __shared__ unsigned sbits[64 * 17];
    const int tid = threadIdx.x;
    const int idx = blockIdx.x * 64 + tid;
    const int b = idx >> 10;
    const int d = idx & (D_DIM - 1);
    const size_t base = (size_t)b * (T_STEPS * D_DIM) + d;
    const float* xp = x + base;
    float* op = out + base;

    float v = 0.0f, a = 0.0f;
    constexpr int U = 32;
    float buf0[U], buf1[U];
#pragma unroll
    for (int i = 0; i < U; ++i) buf0[i] = xp[i * D_DIM];
    for (int it = 0; it < T_STEPS / (2 * U); ++it) {
        const int t0 = it * 2 * U;
#pragma unroll
        for (int i = 0; i < U; ++i) buf1[i] = xp[(t0 + U + i) * D_DIM];
        unsigned wA = 0u;
#pragma unroll
        for (int i = 0; i < U; ++i) { bool f = adlif_step(buf0[i], v, a); wA |= ((unsigned)f) << i; }
        sbits[tid * 17 + it * 2] = wA;
        if (it + 1 < T_STEPS / (2 * U)) {
#pragma unroll
            for (int i = 0; i < U; ++i) buf0[i] = xp[(t0 + 2 * U + i) * D_DIM];
        }
        unsigned wB = 0u;
#pragma unroll
        for (int i = 0; i < U; ++i) { bool f = adlif_step(buf1[i], v, a); wB |= ((unsigned)f) << i; }
        sbits[tid * 17 + it * 2 + 1] = wB;
    }
    for (int w = 0; w < T_STEPS / 32; ++w) {
        const unsigned wb = sbits[tid * 17 + w];
#pragma unroll
        for (int k = 0; k < 32; ++k) {
            float s = (float)((wb >> k) & 1u);
            __builtin_nontemporal_store(s, &op[(size_t)(w * 32 + k) * D_DIM]);
        }
    }
}

extern "C" void kernel_launch(void* const* d_in, const int* in_sizes, int n_in,
                              void* d_out, int out_size, void* d_ws, size_t ws_size,
                              hipStream_t stream) {
    const float* x = (const float*)d_in[0];
    float* out = (float*)d_out;

    const size_t need = (size_t)N_CHAN * (T_STEPS / 32) * sizeof(unsigned);  // 2 MB

    if (ws_size >= need) {
        unsigned* wsbits = (unsigned*)d_ws;
        adlif_scan<<<N_CHAN / 64, 64, 0, stream>>>(x, wsbits);
        adlif_expand<<<32 * 16, 256, 0, stream>>>(wsbits, out);
    } else {
        adlif_single<<<N_CHAN / 64, 64, 0, stream>>>(x, out);
    }
}